// Round 14
// baseline (660.367 us; speedup 1.0000x reference)
//
#include <hip/hip_runtime.h>
#include <hip/hip_bf16.h>

#define M_NODES 32768

using f16x8 = __attribute__((ext_vector_type(8))) _Float16;
using f16x4 = __attribute__((ext_vector_type(4))) _Float16;
using f32x4 = __attribute__((ext_vector_type(4))) float;
typedef unsigned short u16;
typedef unsigned int   u32;

__device__ __forceinline__ u16 f2h(float f){
  _Float16 h = (_Float16)f;
  return __builtin_bit_cast(u16, h);
}
__device__ __forceinline__ float h2f(u16 h){
  return (float)__builtin_bit_cast(_Float16, h);
}
// tanh(x) = 1 - 2/(e^{2x}+1); saturates correctly at +-inf
__device__ __forceinline__ float tanh_fast(float x){
  float t = __builtin_amdgcn_exp2f(x * 2.8853900817779268f);
  return 1.0f - 2.0f * __builtin_amdgcn_rcpf(t + 1.0f);
}

// Raw workgroup barrier: LDS-drain only. Unlike __syncthreads(), does NOT emit
// s_waitcnt vmcnt(0) -> global (weight) loads stay in flight across the barrier;
// the backend inserts counted vmcnt waits at first register use (T4 semantics).
__device__ __forceinline__ void barL(){
  asm volatile("" ::: "memory");                 // compiler ordering fence
  asm volatile("s_waitcnt lgkmcnt(0)");          // commit our ds_writes/ds_reads
  __builtin_amdgcn_s_barrier();
  asm volatile("" ::: "memory");
}

// ---------------- prep: fp32 weights -> fp16 transposed Wt[n][k] in d_ws ----------------
struct PrepPtrs { const float* p[16]; };

__global__ void prep_kernel(PrepPtrs pp, u16* ws){
  const int Bc[16] = {1,6,6,6,3,3,3,3,3,3,3,3,3,3,3,3};
  const int Kc[16] = {32,128,128,128,256,256,256,128,128,128,256,256,256,128,128,128};
  const int Nc[16] = {128,128,128,128,256,256,128,128,128,128,256,256,128,128,128,128};
  const int tot = 1576960;
  for (int i = blockIdx.x*blockDim.x + threadIdx.x; i < tot; i += gridDim.x*blockDim.x){
    int e = i, s = 0;
    while (true){ int sz = Bc[s]*Kc[s]*Nc[s]; if (e < sz) break; e -= sz; ++s; }
    int K = Kc[s], N = Nc[s];
    int kn = K*N;
    int b = e / kn; int r2 = e - b*kn;
    int n = r2 / K; int k = r2 - n*K;
    float v = pp.p[s][(size_t)b*kn + (size_t)k*N + n];
    ws[i] = f2h(v);
  }
}

// ---------------- front 0: e0 = tanh(feats0 @ embed_w + b) (fp32 vector ALU, exact) ----------------
__global__ __launch_bounds__(256) void front0_kernel(const float* __restrict__ feats,
                                                     const float* __restrict__ ew,
                                                     const float* __restrict__ eb,
                                                     float* __restrict__ out){
  __shared__ float fl[2048]; // 64 rows x 32 feats
  const int brow = blockIdx.x * 64;
  const float* f0 = feats + (size_t)brow*32;
#pragma unroll
  for (int it = 0; it < 2; ++it){
    int idx = threadIdx.x + it*256;
    *(float4*)(&fl[idx*4]) = *(const float4*)(f0 + idx*4);
  }
  __syncthreads();
  const int col = threadIdx.x & 127, rh = threadIdx.x >> 7;
  float w[32];
#pragma unroll
  for (int k = 0; k < 32; ++k) w[k] = ew[k*128 + col];
  const float bv = eb[col];
  for (int r = 0; r < 32; ++r){
    int row = rh*32 + r;
    float acc = bv;
#pragma unroll
    for (int k = 0; k < 32; ++k) acc += fl[row*32 + k] * w[k];
    out[(size_t)(brow + row)*128 + col] = tanh_fast(acc);
  }
}

// ---------------- full-preload weight fragments ----------------
// WF<NPAN,NT>: ALL K-panels of this wave's col-tiles in registers. Loaded one full
// stage ahead; raw barriers let the loads stay in flight until first MFMA use.
template<int NPAN, int NT> struct WF { const u16* wrow[NT]; f16x8 b[NPAN][NT]; };

template<int NPAN, int NT, int WS>
__device__ __forceinline__ void wload(WF<NPAN,NT>& R, const u16* __restrict__ wt){
  const int tid = threadIdx.x, lane = tid & 63, nq = tid >> 6;
  const int q = lane >> 4, c = lane & 15;
#pragma unroll
  for (int j = 0; j < NT; ++j){
    int nt = nq*2 + (j & 1) + (j >> 1) * 8;
    R.wrow[j] = wt + (size_t)(nt*16 + c)*WS + q*8;
  }
#pragma unroll
  for (int p = 0; p < NPAN; ++p)
#pragma unroll
    for (int j = 0; j < NT; ++j) R.b[p][j] = *(const f16x8*)(R.wrow[j] + p*32);
}

// 2-panel ring for K=256,N=256 stages (full preload would be 128 VGPRs)
struct WR4 { const u16* wrow[4]; f16x8 b0[4], b1[4]; };
__device__ __forceinline__ void wring_init(WR4& R, const u16* __restrict__ wt){
  const int tid = threadIdx.x, lane = tid & 63, nq = tid >> 6;
  const int q = lane >> 4, c = lane & 15;
#pragma unroll
  for (int j = 0; j < 4; ++j){
    int nt = nq*2 + (j & 1) + (j >> 1) * 8;
    R.wrow[j] = wt + (size_t)(nt*16 + c)*256 + q*8;
  }
#pragma unroll
  for (int j = 0; j < 4; ++j) R.b0[j] = *(const f16x8*)(R.wrow[j]);
#pragma unroll
  for (int j = 0; j < 4; ++j) R.b1[j] = *(const f16x8*)(R.wrow[j] + 32);
}

// ---------------- generic full-preload MFMA stage ----------------
// 64-row block, 4 waves. SWAPPED OPERANDS mfma(W, act): thread holds 4 consecutive
// output cols of one row -> vectorized epilogue. pre() issues the NEXT stage's
// weight loads (they land during epilogue + barrier).
// LDS act buffers: u16 row stride 264 (f16 view) == float row stride 132 (f32 view).
// AMODE: 0 = act fp16 in LDS, 1 = act fp32 in LDS -> hi/lo split (2x MFMA)
// RESMODE: 0 none, 1 fp16 res col<128 only, 2 fp16 res, 3 fp32 res
// OUTMODE: 0 fp16 LDS, 1 fp32 LDS, 2 fp32 global (final)
template<int KLOOP, int N, int WS, int AMODE, int RESMODE, int OUTMODE, bool INPLACE, typename F>
__device__ __forceinline__ void stageF(const u16* inA, u16* outB, const u16* resB,
                                       const float* __restrict__ bias, float* gout,
                                       WF<KLOOP/32, N/64>& W, F&& pre)
{
  const int tid  = threadIdx.x;
  const int lane = tid & 63, nq = tid >> 6;
  const int q = lane >> 4, c = lane & 15;
  constexpr int NT = N / 64;
  constexpr int NP = KLOOP / 32;
  constexpr bool ABURST = (AMODE == 0 && NP == 4);
  const float* inAf = (const float*)inA;
  float*       outF = (float*)outB;
  const float* resF = (const float*)resB;

  f32x4 acc[4][NT];
#pragma unroll
  for (int m = 0; m < 4; ++m)
#pragma unroll
    for (int j = 0; j < NT; ++j) acc[m][j] = (f32x4){0.f,0.f,0.f,0.f};

  // A-burst: all 16 activation fragments issued in one load wave (f16 NP=4 stages)
  f16x8 aall[ABURST ? 16 : 1];
  if (ABURST){
#pragma unroll
    for (int kp = 0; kp < 4; ++kp)
#pragma unroll
      for (int m = 0; m < 4; ++m)
        aall[kp*4 + m] = *(const f16x8*)(&inA[(m*16 + c)*264 + kp*32 + q*8]);
  }

#pragma unroll
  for (int kp = 0; kp < NP; ++kp){
#pragma unroll
    for (int m = 0; m < 4; ++m){
      if (AMODE == 0){
        f16x8 af;
        if (ABURST) af = aall[kp*4 + m];
        else        af = *(const f16x8*)(&inA[(m*16 + c)*264 + kp*32 + q*8]);
#pragma unroll
        for (int j = 0; j < NT; ++j)
          acc[m][j] = __builtin_amdgcn_mfma_f32_16x16x32_f16(W.b[kp][j], af, acc[m][j], 0, 0, 0);
      } else {
        const float* ap = inAf + (m*16 + c)*132 + kp*32 + q*8;
        float4 x0 = *(const float4*)(ap);
        float4 x1 = *(const float4*)(ap + 4);
        float xs[8] = {x0.x,x0.y,x0.z,x0.w,x1.x,x1.y,x1.z,x1.w};
        f16x8 ah, al;
#pragma unroll
        for (int k = 0; k < 8; ++k){
          _Float16 hi = (_Float16)xs[k];
          ah[k] = hi;
          al[k] = (_Float16)(xs[k] - (float)hi);
        }
#pragma unroll
        for (int j = 0; j < NT; ++j){
          acc[m][j] = __builtin_amdgcn_mfma_f32_16x16x32_f16(W.b[kp][j], ah, acc[m][j], 0, 0, 0);
          acc[m][j] = __builtin_amdgcn_mfma_f32_16x16x32_f16(W.b[kp][j], al, acc[m][j], 0, 0, 0);
        }
      }
    }
  }
  pre();                       // issue next stage's weight loads (cross-barrier flight)
  if (INPLACE) barL();
  // vectorized epilogue: per (j,m) one row (m*16+c), 4 consecutive cols
#pragma unroll
  for (int j = 0; j < NT; ++j){
    int nt = nq*2 + (j & 1) + (j >> 1) * 8;
    int col0 = nt*16 + q*4;
    float4 bq = *(const float4*)(bias + col0);
    float bvv[4] = {bq.x, bq.y, bq.z, bq.w};
#pragma unroll
    for (int m = 0; m < 4; ++m){
      int row = m*16 + c;
      float v[4];
#pragma unroll
      for (int r = 0; r < 4; ++r) v[r] = tanh_fast(acc[m][j][r] + bvv[r]);
      if (RESMODE == 2 || (RESMODE == 1 && j < 2)){
        f16x4 rv = *(const f16x4*)(&resB[row*264 + col0]);
#pragma unroll
        for (int r = 0; r < 4; ++r) v[r] += (float)rv[r];
      } else if (RESMODE == 3){
        float4 rf = *(const float4*)(&resF[row*132 + col0]);
        v[0] += rf.x; v[1] += rf.y; v[2] += rf.z; v[3] += rf.w;
      }
      if (OUTMODE == 2){
        float4 o = {v[0], v[1], v[2], v[3]};
        *(float4*)(&gout[(size_t)row*128 + col0]) = o;
      } else if (OUTMODE == 1){
        float4 o = {v[0], v[1], v[2], v[3]};
        *(float4*)(&outF[row*132 + col0]) = o;
      } else {
        f16x4 h;
#pragma unroll
        for (int r = 0; r < 4; ++r) h[r] = (_Float16)v[r];
        *(f16x4*)(&outB[row*264 + col0]) = h;
      }
    }
  }
  barL();
}

// ---------------- ring stage for K=256,N=256 (cw1-full/nw1, cw2/nw2) ----------------
// RESMODE as stageF; INPLACE adds the pre-epilogue barrier. f16 LDS out only.
template<int RESMODE, bool INPLACE, typename F>
__device__ __forceinline__ void stageR(const u16* inA, u16* outB, const u16* resB,
                                       const float* __restrict__ bias, WR4& W, F&& pre)
{
  const int tid  = threadIdx.x;
  const int lane = tid & 63, nq = tid >> 6;
  const int q = lane >> 4, c = lane & 15;

  f32x4 acc[4][4];
#pragma unroll
  for (int m = 0; m < 4; ++m)
#pragma unroll
    for (int j = 0; j < 4; ++j) acc[m][j] = (f32x4){0.f,0.f,0.f,0.f};

#pragma unroll
  for (int kp = 0; kp < 8; ++kp){
    f16x8 bc[4];
    if ((kp & 1) == 0){
#pragma unroll
      for (int j = 0; j < 4; ++j) bc[j] = W.b0[j];
    } else {
#pragma unroll
      for (int j = 0; j < 4; ++j) bc[j] = W.b1[j];
    }
    if (kp + 2 < 8){
      if ((kp & 1) == 0){
#pragma unroll
        for (int j = 0; j < 4; ++j) W.b0[j] = *(const f16x8*)(W.wrow[j] + (kp + 2)*32);
      } else {
#pragma unroll
        for (int j = 0; j < 4; ++j) W.b1[j] = *(const f16x8*)(W.wrow[j] + (kp + 2)*32);
      }
    }
#pragma unroll
    for (int m = 0; m < 4; ++m){
      f16x8 af = *(const f16x8*)(&inA[(m*16 + c)*264 + kp*32 + q*8]);
#pragma unroll
      for (int j = 0; j < 4; ++j)
        acc[m][j] = __builtin_amdgcn_mfma_f32_16x16x32_f16(bc[j], af, acc[m][j], 0, 0, 0);
    }
  }
  pre();
  if (INPLACE) barL();   // in-place: all A reads complete before overwrite
#pragma unroll
  for (int j = 0; j < 4; ++j){
    int nt = nq*2 + (j & 1) + (j >> 1) * 8;
    int col0 = nt*16 + q*4;
    float4 bq = *(const float4*)(bias + col0);
    float bvv[4] = {bq.x, bq.y, bq.z, bq.w};
#pragma unroll
    for (int m = 0; m < 4; ++m){
      int row = m*16 + c;
      float v[4];
#pragma unroll
      for (int r = 0; r < 4; ++r) v[r] = tanh_fast(acc[m][j][r] + bvv[r]);
      if (RESMODE == 2 || (RESMODE == 1 && j < 2)){
        f16x4 rv = *(const f16x4*)(&resB[row*264 + col0]);
#pragma unroll
        for (int r = 0; r < 4; ++r) v[r] += (float)rv[r];
      }
      f16x4 h;
#pragma unroll
      for (int r = 0; r < 4; ++r) h[r] = (_Float16)v[r];
      *(f16x4*)(&outB[row*264 + col0]) = h;
    }
  }
  barL();
}

// embed stage: act from global fp32 feats (K=32) hi/lo split; weights in WF<1,2>
template<typename F>
__device__ __forceinline__ void embed_stage(const float* __restrict__ featsRow,
                                            u16* outB, const float* __restrict__ bias,
                                            WF<1,2>& W, F&& pre)
{
  const int tid  = threadIdx.x;
  const int lane = tid & 63, nq = tid >> 6;
  const int q = lane >> 4, c = lane & 15;
  f32x4 acc[4][2];
#pragma unroll
  for (int m = 0; m < 4; ++m){ acc[m][0] = (f32x4){0,0,0,0}; acc[m][1] = (f32x4){0,0,0,0}; }
#pragma unroll
  for (int m = 0; m < 4; ++m){
    int row = m*16 + c;
    const float* fp = featsRow + (size_t)row*32 + q*8;
    float4 a0 = *(const float4*)(fp);
    float4 a1 = *(const float4*)(fp + 4);
    float xs[8] = {a0.x,a0.y,a0.z,a0.w,a1.x,a1.y,a1.z,a1.w};
    f16x8 ah, al;
#pragma unroll
    for (int k = 0; k < 8; ++k){
      _Float16 hi = (_Float16)xs[k];
      ah[k] = hi;
      al[k] = (_Float16)(xs[k] - (float)hi);
    }
#pragma unroll
    for (int j = 0; j < 2; ++j){
      acc[m][j] = __builtin_amdgcn_mfma_f32_16x16x32_f16(W.b[0][j], ah, acc[m][j], 0, 0, 0);
      acc[m][j] = __builtin_amdgcn_mfma_f32_16x16x32_f16(W.b[0][j], al, acc[m][j], 0, 0, 0);
    }
  }
  pre();
#pragma unroll
  for (int j = 0; j < 2; ++j){
    int nt = nq*2 + j;
    int col0 = nt*16 + q*4;
    float4 bq = *(const float4*)(bias + col0);
    float bvv[4] = {bq.x, bq.y, bq.z, bq.w};
#pragma unroll
    for (int m = 0; m < 4; ++m){
      int row = m*16 + c;
      f16x4 h;
#pragma unroll
      for (int r = 0; r < 4; ++r) h[r] = (_Float16)tanh_fast(acc[m][j][r] + bvv[r]);
      *(f16x4*)(&outB[row*264 + col0]) = h;
    }
  }
  barL();
}

struct FrontArgs {
  const float* feats; const int* pred;
  const u16* ws;
  float* out;
  const float* embed_b;
  const float* mp_b1; const float* mp_b2; const float* mp_b3;
  const float* cw_b1; const float* cw_b2; const float* cw_b3;
  const float* ch_b1; const float* ch_b2; const float* ch_b3;
  const float* nw_b1; const float* nw_b2; const float* nw_b3;
  const float* nh_b1; const float* nh_b2; const float* nh_b3;
  int l, d;
};

// LDS: P[64][264] u16 + Q[64][264] u16 = 67584 B dynamic -> 2 blocks/CU
__global__ __launch_bounds__(256, 2) void front_kernel(FrontArgs A)
{
  extern __shared__ u16 lds[];
  u16* P  = lds;
  u16* Q  = lds + 16896;
  const int brow = blockIdx.x * 64;
  const int d = A.d;
  const u16* ws = A.ws;
  const int d0 = d*2, d1 = d*2 + 1;

  WF<4,2> w1, w2, w3, w4, w5, w6, wch1, wch2, wch3, wnh1, wnh2, wnh3;
  WF<1,2> wemb;
  WF<4,4> wcw1;
  WF<8,2> wcw3, wnw3;
  WR4 rcw2, rnw1, rnw2;

  // stage-1 weights in flight while the gather runs
  wload<4,2,128>(w1, ws + 4096 + (size_t)d0*16384);

  // ---- gather: s = sum_k prev[idx[m][k]] -> P as fp32 [64][132] ----
  {
    float* Pf = (float*)P;
    const float* prev = A.out + (size_t)(A.l - 1) * M_NODES * 128;
    const int c4 = threadIdx.x & 31;
    const int r0 = threadIdx.x >> 5;
#pragma unroll
    for (int rr = 0; rr < 8; ++rr){
      int row = r0 + rr*8;
      const int* ip = A.pred + ((size_t)(A.l - 1) * M_NODES + brow + row) * 8;
      float sx=0.f, sy=0.f, sz=0.f, sw=0.f;
#pragma unroll
      for (int p = 0; p < 8; ++p){
        const float4 v = *(const float4*)(prev + (size_t)ip[p]*128 + c4*4);
        sx += v.x; sy += v.y; sz += v.z; sw += v.w;
      }
      float4 o = {sx, sy, sz, sw};
      *(float4*)(&Pf[row*132 + c4*4]) = o;
    }
  }
  barL();

  // 1. h1 = tanh(s @ w1)               A=P.f32 -> Q.f16
  stageF<128,128,128, 1,0,0,false>(P, Q, nullptr, A.mp_b1 + d0*128, nullptr, w1,
    [&]{ wload<4,2,128>(w2, ws + 102400 + (size_t)d0*16384); });
  // 2. h2s = tanh(h1 @ w2) + s         A=Q.f16, res=P.f32 -> P.f32 (per-thread identity)
  stageF<128,128,128, 0,3,1,false>(Q, P, P, A.mp_b2 + d0*128, nullptr, w2,
    [&]{ wload<4,2,128>(w3, ws + 200704 + (size_t)d0*16384); });
  // 3. r1 = tanh(h2s @ w3)             A=P.f32 -> Q.f16
  stageF<128,128,128, 1,0,0,false>(P, Q, nullptr, A.mp_b3 + d0*128, nullptr, w3,
    [&]{ wload<4,2,128>(w4, ws + 4096 + (size_t)d1*16384); });
  // 4. h1b = tanh(r1 @ w1)             A=Q.f16 -> P.f16
  stageF<128,128,128, 0,0,0,false>(Q, P, nullptr, A.mp_b1 + d1*128, nullptr, w4,
    [&]{ wload<4,2,128>(w5, ws + 102400 + (size_t)d1*16384); });
  // 5. h2r = tanh(h1b @ w2) + r1       A=P.f16, res=Q.f16 -> P.f32 (INPLACE)
  stageF<128,128,128, 0,2,1,true >(P, P, Q, A.mp_b2 + d1*128, nullptr, w5,
    [&]{ wload<4,2,128>(w6, ws + 200704 + (size_t)d1*16384); });
  // 6. r = tanh(h2r @ w3)              A=P.f32 -> Q.f16[128:256)
  stageF<128,128,128, 1,0,0,false>(P, Q + 128, nullptr, A.mp_b3 + d1*128, nullptr, w6,
    [&]{ wload<1,2,32>(wemb, ws); });
  // 7. e -> Q.f16[0:128)   (Q = [e | r])
  embed_stage(A.feats + ((size_t)A.l * M_NODES + brow) * 32, Q, A.embed_b, wemb,
    [&]{ wload<4,4,256>(wcw1, ws + 299008 + (size_t)d*65536); });
  // ---- comb_wide resnet on [e,0] (zero-trick: K=128 genuine) ----
  stageF<128,256,256, 0,0,0,false>(Q, P, nullptr, A.cw_b1 + d*256, nullptr, wcw1,
    [&]{ wring_init(rcw2, ws + 495616 + (size_t)d*65536); });
  stageR<1,true>(P, P, Q, A.cw_b2 + d*256, rcw2,
    [&]{ wload<8,2,256>(wcw3, ws + 692224 + (size_t)d*32768); });
  stageF<256,128,256, 0,0,0,false>(P, Q, nullptr, A.cw_b3 + d*128, nullptr, wcw3,
    [&]{ wload<4,2,128>(wch1, ws + 790528 + (size_t)d*16384); });
  // ---- comb_h resnet ----
  stageF<128,128,128, 0,0,0,false>(Q, P, nullptr, A.ch_b1 + d*128, nullptr, wch1,
    [&]{ wload<4,2,128>(wch2, ws + 839680 + (size_t)d*16384); });
  stageF<128,128,128, 0,2,0,true >(P, P, Q, A.ch_b2 + d*128, nullptr, wch2,
    [&]{ wload<4,2,128>(wch3, ws + 888832 + (size_t)d*16384); });
  stageF<128,128,128, 0,0,0,false>(P, Q, nullptr, A.ch_b3 + d*128, nullptr, wch3,
    [&]{ wring_init(rnw1, ws + 937984 + (size_t)d*65536); });
  // ---- node_wide resnet on x2 = [e''|r] in Q : FULL K=256 (bug fixed) ----
  stageR<0,false>(Q, P, nullptr, A.nw_b1 + d*256, rnw1,
    [&]{ wring_init(rnw2, ws + 1134592 + (size_t)d*65536); });
  stageR<2,true>(P, P, Q, A.nw_b2 + d*256, rnw2,
    [&]{ wload<8,2,256>(wnw3, ws + 1331200 + (size_t)d*32768); });
  stageF<256,128,256, 0,0,0,false>(P, Q, nullptr, A.nw_b3 + d*128, nullptr, wnw3,
    [&]{ wload<4,2,128>(wnh1, ws + 1429504 + (size_t)d*16384); });
  // ---- node_h resnet; final writes fp32 to global ----
  stageF<128,128,128, 0,0,0,false>(Q, P, nullptr, A.nh_b1 + d*128, nullptr, wnh1,
    [&]{ wload<4,2,128>(wnh2, ws + 1478656 + (size_t)d*16384); });
  stageF<128,128,128, 0,2,0,true >(P, P, Q, A.nh_b2 + d*128, nullptr, wnh2,
    [&]{ wload<4,2,128>(wnh3, ws + 1527808 + (size_t)d*16384); });
  float* gout = A.out + ((size_t)A.l * M_NODES + brow) * 128;
  stageF<128,128,128, 0,0,2,false>(P, nullptr, nullptr, A.nh_b3 + d*128, gout, wnh3, []{});
}

extern "C" void kernel_launch(void* const* d_in, const int* in_sizes, int n_in,
                              void* d_out, int out_size, void* d_ws, size_t ws_size,
                              hipStream_t stream)
{
  (void)in_sizes; (void)n_in; (void)out_size; (void)ws_size;
  const float* feats = (const float*)d_in[0];
  const int*   pred  = (const int*)d_in[1];
  u16*   ws  = (u16*)d_ws;
  float* out = (float*)d_out;

  PrepPtrs pp;
  const int wIdx[16] = {2,4,6,8,10,12,14,16,18,20,22,24,26,28,30,32};
  for (int i = 0; i < 16; ++i) pp.p[i] = (const float*)d_in[wIdx[i]];
  prep_kernel<<<2048, 256, 0, stream>>>(pp, ws);

  front0_kernel<<<M_NODES/64, 256, 0, stream>>>(feats, (const float*)d_in[2], (const float*)d_in[3], out);

  const size_t LDSB = (size_t)(2*64*264) * sizeof(u16); // 67584 B
  (void)hipFuncSetAttribute((const void*)front_kernel,
                            hipFuncAttributeMaxDynamicSharedMemorySize, (int)LDSB);

  FrontArgs A;
  A.feats = feats; A.pred = pred; A.ws = ws; A.out = out;
  A.embed_b = (const float*)d_in[3];
  A.mp_b1 = (const float*)d_in[5];  A.mp_b2 = (const float*)d_in[7];  A.mp_b3 = (const float*)d_in[9];
  A.cw_b1 = (const float*)d_in[11]; A.cw_b2 = (const float*)d_in[13]; A.cw_b3 = (const float*)d_in[15];
  A.ch_b1 = (const float*)d_in[17]; A.ch_b2 = (const float*)d_in[19]; A.ch_b3 = (const float*)d_in[21];
  A.nw_b1 = (const float*)d_in[23]; A.nw_b2 = (const float*)d_in[25]; A.nw_b3 = (const float*)d_in[27];
  A.nh_b1 = (const float*)d_in[29]; A.nh_b2 = (const float*)d_in[31]; A.nh_b3 = (const float*)d_in[33];

  for (int l = 1; l < 8; ++l){
    A.l = l;
    A.d = (l - 1 < 2) ? (l - 1) : 2;
    front_kernel<<<M_NODES/64, 256, LDSB, stream>>>(A);
  }
}

// Round 15
// 645.391 us; speedup vs baseline: 1.0232x; 1.0232x over previous
//
#include <hip/hip_runtime.h>
#include <hip/hip_bf16.h>

#define M_NODES 32768

using f16x8 = __attribute__((ext_vector_type(8))) _Float16;
using f16x4 = __attribute__((ext_vector_type(4))) _Float16;
using f32x4 = __attribute__((ext_vector_type(4))) float;
typedef unsigned short u16;
typedef unsigned int   u32;

__device__ __forceinline__ float h2f(u16 h){
  return (float)__builtin_bit_cast(_Float16, h);
}
// tanh(x) = 1 - 2/(e^{2x}+1); saturates correctly at +-inf
__device__ __forceinline__ float tanh_fast(float x){
  float t = __builtin_amdgcn_exp2f(x * 2.8853900817779268f);
  return 1.0f - 2.0f * __builtin_amdgcn_rcpf(t + 1.0f);
}
__device__ __forceinline__ u16 f2h(float f){
  _Float16 h = (_Float16)f;
  return __builtin_bit_cast(u16, h);
}

// ---------------- prep: fp32 weights -> fp16 transposed Wt[n][k] in d_ws ----------------
struct PrepPtrs { const float* p[16]; };

__global__ void prep_kernel(PrepPtrs pp, u16* ws){
  const int Bc[16] = {1,6,6,6,3,3,3,3,3,3,3,3,3,3,3,3};
  const int Kc[16] = {32,128,128,128,256,256,256,128,128,128,256,256,256,128,128,128};
  const int Nc[16] = {128,128,128,128,256,256,128,128,128,128,256,256,128,128,128,128};
  const int tot = 1576960;
  for (int i = blockIdx.x*blockDim.x + threadIdx.x; i < tot; i += gridDim.x*blockDim.x){
    int e = i, s = 0;
    while (true){ int sz = Bc[s]*Kc[s]*Nc[s]; if (e < sz) break; e -= sz; ++s; }
    int K = Kc[s], N = Nc[s];
    int kn = K*N;
    int b = e / kn; int r2 = e - b*kn;
    int n = r2 / K; int k = r2 - n*K;
    float v = pp.p[s][(size_t)b*kn + (size_t)k*N + n];
    ws[i] = f2h(v);
  }
}

// ---------------- front 0: e0 = tanh(feats0 @ embed_w + b) (fp32 vector ALU, exact) ----------------
__global__ __launch_bounds__(256) void front0_kernel(const float* __restrict__ feats,
                                                     const float* __restrict__ ew,
                                                     const float* __restrict__ eb,
                                                     float* __restrict__ out){
  __shared__ float fl[2048]; // 64 rows x 32 feats
  const int brow = blockIdx.x * 64;
  const float* f0 = feats + (size_t)brow*32;
#pragma unroll
  for (int it = 0; it < 2; ++it){
    int idx = threadIdx.x + it*256;
    *(float4*)(&fl[idx*4]) = *(const float4*)(f0 + idx*4);
  }
  __syncthreads();
  const int col = threadIdx.x & 127, rh = threadIdx.x >> 7;
  float w[32];
#pragma unroll
  for (int k = 0; k < 32; ++k) w[k] = ew[k*128 + col];
  const float bv = eb[col];
  for (int r = 0; r < 32; ++r){
    int row = rh*32 + r;
    float acc = bv;
#pragma unroll
    for (int k = 0; k < 32; ++k) acc += fl[row*32 + k] * w[k];
    out[(size_t)(brow + row)*128 + col] = tanh_fast(acc);
  }
}

// ---------------- weight ring: 2-panel register prefetch, hoisted ACROSS stages ----------------
// Next stage's first two weight panels depend on nothing -> issue them before the
// current stage's epilogue/barrier so L2 latency hides under tanh + barrier.
struct WRing {
  const u16* wrow[4];
  f16x8 b0[4], b1[4];
};

template<int N, int WS, int NP>
__device__ __forceinline__ void wpreload(WRing& R, const u16* __restrict__ wt, int phase){
  const int tid  = threadIdx.x;
  const int lane = tid & 63, nq = tid >> 6;
  const int q = lane >> 4, c = lane & 15;
  constexpr int NT = N / 64;
  const int msk = NP - 1;
  const int p0 = phase & msk, p1 = (phase + 1) & msk;
#pragma unroll
  for (int j = 0; j < NT; ++j){
    int nt = nq*2 + (j & 1) + (j >> 1) * 8;
    R.wrow[j] = wt + (size_t)(nt*16 + c)*WS + q*8;
  }
#pragma unroll
  for (int j = 0; j < NT; ++j) R.b0[j] = *(const f16x8*)(R.wrow[j] + p0*32);
#pragma unroll
  for (int j = 0; j < NT; ++j) R.b1[j] = *(const f16x8*)(R.wrow[j] + p1*32);
}

// ---------------- generic MFMA stage (fp16 MFMA, fp32 accumulate) ----------------
// 64-row block, 4 waves. SWAPPED OPERANDS mfma(W, act): thread holds 4 consecutive
// output cols of one row -> vectorized epilogue. Weights via WRing (cross-stage
// preloaded). A-BURST: for NP=4 f16 stages issue all 16 ds_read_b128 up front
// (one latency exposure instead of 4 chained). Per-block K-panel phase rotation.
// LDS act buffers: u16 row stride 264 (f16 view) == float row stride 132 (f32 view).
// AMODE: 0 = act fp16 in LDS, 1 = act fp32 in LDS -> hi/lo split (2x MFMA)
// RESMODE: 0 none, 1 fp16 res col<128 only, 2 fp16 res, 3 fp32 res
// OUTMODE: 0 fp16 LDS, 1 fp32 LDS, 2 fp32 global (final)
// NN/NWS/NNP: next stage's preload params (NN==0 -> none)
template<int KLOOP, int N, int WS, int AMODE, int RESMODE, int OUTMODE, bool INPLACE,
         int NN, int NWS, int NNP>
__device__ __forceinline__ void mm_stage(const u16* inA, u16* outB, const u16* resB,
                                         const float* __restrict__ bias, float* gout,
                                         int phase, WRing& cur, WRing& nxt,
                                         const u16* __restrict__ wtnext)
{
  const int tid  = threadIdx.x;
  const int lane = tid & 63, nq = tid >> 6;
  const int q = lane >> 4, c = lane & 15;
  constexpr int NT = N / 64;      // col tiles per wave (2 or 4)
  constexpr int NP = KLOOP / 32;  // k-panels (4 or 8)
  constexpr bool ABURST = (AMODE == 0 && NP == 4);
  const float* inAf = (const float*)inA;
  float*       outF = (float*)outB;
  const float* resF = (const float*)resB;
  const int msk = NP - 1;
  const int ph = phase & msk;

  f32x4 acc[4][NT];
#pragma unroll
  for (int m = 0; m < 4; ++m)
#pragma unroll
    for (int j = 0; j < NT; ++j) acc[m][j] = (f32x4){0.f,0.f,0.f,0.f};

  // A-burst: all 16 activation fragments in one load wave
  f16x8 aall[ABURST ? 16 : 1];
  if (ABURST){
#pragma unroll
    for (int kp = 0; kp < 4; ++kp){
      int kpp = (ph + kp) & 3;
#pragma unroll
      for (int m = 0; m < 4; ++m)
        aall[kp*4 + m] = *(const f16x8*)(&inA[(m*16 + c)*264 + kpp*32 + q*8]);
    }
  }

#pragma unroll
  for (int kp = 0; kp < NP; ++kp){
    const int kpp = (ph + kp) & msk;
    f16x8 bc[NT];
    if ((kp & 1) == 0){
#pragma unroll
      for (int j = 0; j < NT; ++j) bc[j] = cur.b0[j];
    } else {
#pragma unroll
      for (int j = 0; j < NT; ++j) bc[j] = cur.b1[j];
    }
    if (kp + 2 < NP){
      int kn = (ph + kp + 2) & msk;
      if ((kp & 1) == 0){
#pragma unroll
        for (int j = 0; j < NT; ++j) cur.b0[j] = *(const f16x8*)(cur.wrow[j] + kn*32);
      } else {
#pragma unroll
        for (int j = 0; j < NT; ++j) cur.b1[j] = *(const f16x8*)(cur.wrow[j] + kn*32);
      }
    }
#pragma unroll
    for (int m = 0; m < 4; ++m){
      if (AMODE == 0){
        f16x8 af;
        if (ABURST) af = aall[kp*4 + m];
        else        af = *(const f16x8*)(&inA[(m*16 + c)*264 + kpp*32 + q*8]);
#pragma unroll
        for (int j = 0; j < NT; ++j)
          acc[m][j] = __builtin_amdgcn_mfma_f32_16x16x32_f16(bc[j], af, acc[m][j], 0, 0, 0);
      } else {
        const float* ap = inAf + (m*16 + c)*132 + kpp*32 + q*8;
        float4 x0 = *(const float4*)(ap);
        float4 x1 = *(const float4*)(ap + 4);
        float xs[8] = {x0.x,x0.y,x0.z,x0.w,x1.x,x1.y,x1.z,x1.w};
        f16x8 ah, al;
#pragma unroll
        for (int k = 0; k < 8; ++k){
          _Float16 hi = (_Float16)xs[k];
          ah[k] = hi;
          al[k] = (_Float16)(xs[k] - (float)hi);
        }
#pragma unroll
        for (int j = 0; j < NT; ++j){
          acc[m][j] = __builtin_amdgcn_mfma_f32_16x16x32_f16(bc[j], ah, acc[m][j], 0, 0, 0);
          acc[m][j] = __builtin_amdgcn_mfma_f32_16x16x32_f16(bc[j], al, acc[m][j], 0, 0, 0);
        }
      }
    }
  }
  // hoisted preload of NEXT stage's weight panels (lands during epilogue+barrier)
  if constexpr (NN > 0) wpreload<NN, NWS, NNP>(nxt, wtnext, phase);
  if (INPLACE) __syncthreads();
  // vectorized epilogue: per (j,m) one row (m*16+c), 4 consecutive cols
#pragma unroll
  for (int j = 0; j < NT; ++j){
    int nt = nq*2 + (j & 1) + (j >> 1) * 8;
    int col0 = nt*16 + q*4;
    float4 bq = *(const float4*)(bias + col0);
    float bvv[4] = {bq.x, bq.y, bq.z, bq.w};
#pragma unroll
    for (int m = 0; m < 4; ++m){
      int row = m*16 + c;
      float v[4];
#pragma unroll
      for (int r = 0; r < 4; ++r) v[r] = tanh_fast(acc[m][j][r] + bvv[r]);
      if (RESMODE == 2 || (RESMODE == 1 && j < 2)){
        f16x4 rv = *(const f16x4*)(&resB[row*264 + col0]);
#pragma unroll
        for (int r = 0; r < 4; ++r) v[r] += (float)rv[r];
      } else if (RESMODE == 3){
        float4 rf = *(const float4*)(&resF[row*132 + col0]);
        v[0] += rf.x; v[1] += rf.y; v[2] += rf.z; v[3] += rf.w;
      }
      if (OUTMODE == 2){
        float4 o = {v[0], v[1], v[2], v[3]};
        *(float4*)(&gout[(size_t)row*128 + col0]) = o;
      } else if (OUTMODE == 1){
        float4 o = {v[0], v[1], v[2], v[3]};
        *(float4*)(&outF[row*132 + col0]) = o;
      } else {
        f16x4 h;
#pragma unroll
        for (int r = 0; r < 4; ++r) h[r] = (_Float16)v[r];
        *(f16x4*)(&outB[row*264 + col0]) = h;
      }
    }
  }
  __syncthreads();
}

// embed stage: act from global fp32 feats (K=32) hi/lo split; weights from ring.b0
__device__ __forceinline__ void embed_stage(const float* __restrict__ featsRow,
                                            u16* outB, const float* __restrict__ bias,
                                            int phase, WRing& cur, WRing& nxt,
                                            const u16* __restrict__ wtnext)
{
  const int tid  = threadIdx.x;
  const int lane = tid & 63, nq = tid >> 6;
  const int q = lane >> 4, c = lane & 15;
  f32x4 acc[4][2];
#pragma unroll
  for (int m = 0; m < 4; ++m){ acc[m][0] = (f32x4){0,0,0,0}; acc[m][1] = (f32x4){0,0,0,0}; }
#pragma unroll
  for (int m = 0; m < 4; ++m){
    int row = m*16 + c;
    const float* fp = featsRow + (size_t)row*32 + q*8;
    float4 a0 = *(const float4*)(fp);
    float4 a1 = *(const float4*)(fp + 4);
    float xs[8] = {a0.x,a0.y,a0.z,a0.w,a1.x,a1.y,a1.z,a1.w};
    f16x8 ah, al;
#pragma unroll
    for (int k = 0; k < 8; ++k){
      _Float16 hi = (_Float16)xs[k];
      ah[k] = hi;
      al[k] = (_Float16)(xs[k] - (float)hi);
    }
#pragma unroll
    for (int j = 0; j < 2; ++j){
      acc[m][j] = __builtin_amdgcn_mfma_f32_16x16x32_f16(cur.b0[j], ah, acc[m][j], 0, 0, 0);
      acc[m][j] = __builtin_amdgcn_mfma_f32_16x16x32_f16(cur.b0[j], al, acc[m][j], 0, 0, 0);
    }
  }
  wpreload<256, 256, 4>(nxt, wtnext, phase);   // next = comb_wide w1
#pragma unroll
  for (int j = 0; j < 2; ++j){
    int nt = nq*2 + j;
    int col0 = nt*16 + q*4;
    float4 bq = *(const float4*)(bias + col0);
    float bvv[4] = {bq.x, bq.y, bq.z, bq.w};
#pragma unroll
    for (int m = 0; m < 4; ++m){
      int row = m*16 + c;
      f16x4 h;
#pragma unroll
      for (int r = 0; r < 4; ++r) h[r] = (_Float16)tanh_fast(acc[m][j][r] + bvv[r]);
      *(f16x4*)(&outB[row*264 + col0]) = h;
    }
  }
  __syncthreads();
}

struct FrontArgs {
  const float* feats; const int* pred;
  const u16* ws;
  float* out;
  const float* embed_b;
  const float* mp_b1; const float* mp_b2; const float* mp_b3;
  const float* cw_b1; const float* cw_b2; const float* cw_b3;
  const float* ch_b1; const float* ch_b2; const float* ch_b3;
  const float* nw_b1; const float* nw_b2; const float* nw_b3;
  const float* nh_b1; const float* nh_b2; const float* nh_b3;
  int l, d;
};

// LDS: P[64][264] u16 + Q[64][264] u16 = 67584 B dynamic -> 2 blocks/CU
__global__ __launch_bounds__(256, 2) void front_kernel(FrontArgs A)
{
  extern __shared__ u16 lds[];
  u16* P  = lds;
  u16* Q  = lds + 16896;
  const int brow = blockIdx.x * 64;
  const int d = A.d;
  const u16* ws = A.ws;
  const int ph = blockIdx.x;   // per-block K-panel phase
  const int d0 = d*2, d1 = d*2 + 1;

  WRing rA, rB;
  // stage-1 weights in flight while the gather runs
  wpreload<128, 128, 4>(rA, ws + 4096 + (size_t)d0*16384, ph);

  // ---- gather: s = sum_k prev[idx[m][k]] -> P as fp32 [64][132] ----
  {
    float* Pf = (float*)P;
    const float* prev = A.out + (size_t)(A.l - 1) * M_NODES * 128;
    const int c4 = threadIdx.x & 31;  // float4 column group
    const int r0 = threadIdx.x >> 5;  // 8 rows in flight
#pragma unroll
    for (int rr = 0; rr < 8; ++rr){
      int row = r0 + rr*8;
      const int* ip = A.pred + ((size_t)(A.l - 1) * M_NODES + brow + row) * 8;
      float sx=0.f, sy=0.f, sz=0.f, sw=0.f;
#pragma unroll
      for (int p = 0; p < 8; ++p){
        const float4 v = *(const float4*)(prev + (size_t)ip[p]*128 + c4*4);
        sx += v.x; sy += v.y; sz += v.z; sw += v.w;
      }
      float4 o = {sx, sy, sz, sw};
      *(float4*)(&Pf[row*132 + c4*4]) = o;
    }
  }
  __syncthreads();

  // 1. h1 = tanh(s @ w1)               A=P.f32 -> Q.f16
  mm_stage<128,128,128, 1,0,0,false, 128,128,4>(P, Q, nullptr, A.mp_b1 + d0*128, nullptr, ph, rA, rB, ws + 102400 + (size_t)d0*16384);
  // 2. h2s = tanh(h1 @ w2) + s         A=Q.f16, res=P.f32 -> P.f32
  mm_stage<128,128,128, 0,3,1,false, 128,128,4>(Q, P, P, A.mp_b2 + d0*128, nullptr, ph, rB, rA, ws + 200704 + (size_t)d0*16384);
  // 3. r1 = tanh(h2s @ w3)             A=P.f32 -> Q.f16
  mm_stage<128,128,128, 1,0,0,false, 128,128,4>(P, Q, nullptr, A.mp_b3 + d0*128, nullptr, ph, rA, rB, ws + 4096 + (size_t)d1*16384);
  // 4. h1b = tanh(r1 @ w1)             A=Q.f16 -> P.f16
  mm_stage<128,128,128, 0,0,0,false, 128,128,4>(Q, P, nullptr, A.mp_b1 + d1*128, nullptr, ph, rB, rA, ws + 102400 + (size_t)d1*16384);
  // 5. h2r = tanh(h1b @ w2) + r1       A=P.f16, res=Q.f16 -> P.f32 (INPLACE)
  mm_stage<128,128,128, 0,2,1,true , 128,128,4>(P, P, Q, A.mp_b2 + d1*128, nullptr, ph, rA, rB, ws + 200704 + (size_t)d1*16384);
  // 6. r = tanh(h2r @ w3)              A=P.f32 -> Q.f16[128:256); next = embed (K=32, 1 panel)
  mm_stage<128,128,128, 1,0,0,false, 128,32,1>(P, Q + 128, nullptr, A.mp_b3 + d1*128, nullptr, ph, rB, rA, ws);
  // 7. e -> Q.f16[0:128)   (Q = [e | r]); next = cw1
  embed_stage(A.feats + ((size_t)A.l * M_NODES + brow) * 32, Q, A.embed_b, ph, rA, rB, ws + 299008 + (size_t)d*65536);
  // ---- comb_wide resnet on [e,0] (zero-trick: K=128) ----
  mm_stage<128,256,256, 0,0,0,false, 256,256,8>(Q, P, nullptr, A.cw_b1 + d*256, nullptr, ph, rB, rA, ws + 495616 + (size_t)d*65536);
  mm_stage<256,256,256, 0,1,0,true , 128,256,8>(P, P, Q, A.cw_b2 + d*256, nullptr, ph, rA, rB, ws + 692224 + (size_t)d*32768);
  mm_stage<256,128,256, 0,0,0,false, 128,128,4>(P, Q, nullptr, A.cw_b3 + d*128, nullptr, ph, rB, rA, ws + 790528 + (size_t)d*16384);
  // ---- comb_h resnet ----
  mm_stage<128,128,128, 0,0,0,false, 128,128,4>(Q, P, nullptr, A.ch_b1 + d*128, nullptr, ph, rA, rB, ws + 839680 + (size_t)d*16384);
  mm_stage<128,128,128, 0,2,0,true , 128,128,4>(P, P, Q, A.ch_b2 + d*128, nullptr, ph, rB, rA, ws + 888832 + (size_t)d*16384);
  mm_stage<128,128,128, 0,0,0,false, 256,256,8>(P, Q, nullptr, A.ch_b3 + d*128, nullptr, ph, rA, rB, ws + 937984 + (size_t)d*65536);
  // ---- node_wide resnet on x2 = [e''|r] in Q ----
  mm_stage<256,256,256, 0,0,0,false, 256,256,8>(Q, P, nullptr, A.nw_b1 + d*256, nullptr, ph, rB, rA, ws + 1134592 + (size_t)d*65536);
  mm_stage<256,256,256, 0,2,0,true , 128,256,8>(P, P, Q, A.nw_b2 + d*256, nullptr, ph, rA, rB, ws + 1331200 + (size_t)d*32768);
  mm_stage<256,128,256, 0,0,0,false, 128,128,4>(P, Q, nullptr, A.nw_b3 + d*128, nullptr, ph, rB, rA, ws + 1429504 + (size_t)d*16384);
  // ---- node_h resnet; final writes fp32 to global ----
  mm_stage<128,128,128, 0,0,0,false, 128,128,4>(Q, P, nullptr, A.nh_b1 + d*128, nullptr, ph, rA, rB, ws + 1478656 + (size_t)d*16384);
  mm_stage<128,128,128, 0,2,0,true , 128,128,4>(P, P, Q, A.nh_b2 + d*128, nullptr, ph, rB, rA, ws + 1527808 + (size_t)d*16384);
  float* gout = A.out + ((size_t)A.l * M_NODES + brow) * 128;
  mm_stage<128,128,128, 0,0,2,false, 0,0,1>(P, nullptr, nullptr, A.nh_b3 + d*128, gout, ph, rA, rB, nullptr);
}

extern "C" void kernel_launch(void* const* d_in, const int* in_sizes, int n_in,
                              void* d_out, int out_size, void* d_ws, size_t ws_size,
                              hipStream_t stream)
{
  (void)in_sizes; (void)n_in; (void)out_size; (void)ws_size;
  const float* feats = (const float*)d_in[0];
  const int*   pred  = (const int*)d_in[1];
  u16*   ws  = (u16*)d_ws;
  float* out = (float*)d_out;

  PrepPtrs pp;
  const int wIdx[16] = {2,4,6,8,10,12,14,16,18,20,22,24,26,28,30,32};
  for (int i = 0; i < 16; ++i) pp.p[i] = (const float*)d_in[wIdx[i]];
  prep_kernel<<<2048, 256, 0, stream>>>(pp, ws);

  front0_kernel<<<M_NODES/64, 256, 0, stream>>>(feats, (const float*)d_in[2], (const float*)d_in[3], out);

  const size_t LDSB = (size_t)(2*64*264) * sizeof(u16); // 67584 B
  (void)hipFuncSetAttribute((const void*)front_kernel,
                            hipFuncAttributeMaxDynamicSharedMemorySize, (int)LDSB);

  FrontArgs A;
  A.feats = feats; A.pred = pred; A.ws = ws; A.out = out;
  A.embed_b = (const float*)d_in[3];
  A.mp_b1 = (const float*)d_in[5];  A.mp_b2 = (const float*)d_in[7];  A.mp_b3 = (const float*)d_in[9];
  A.cw_b1 = (const float*)d_in[11]; A.cw_b2 = (const float*)d_in[13]; A.cw_b3 = (const float*)d_in[15];
  A.ch_b1 = (const float*)d_in[17]; A.ch_b2 = (const float*)d_in[19]; A.ch_b3 = (const float*)d_in[21];
  A.nw_b1 = (const float*)d_in[23]; A.nw_b2 = (const float*)d_in[25]; A.nw_b3 = (const float*)d_in[27];
  A.nh_b1 = (const float*)d_in[29]; A.nh_b2 = (const float*)d_in[31]; A.nh_b3 = (const float*)d_in[33];

  for (int l = 1; l < 8; ++l){
    A.l = l;
    A.d = (l - 1 < 2) ? (l - 1) : 2;
    front_kernel<<<M_NODES/64, 256, LDSB, stream>>>(A);
  }
}

// Round 16
// 631.629 us; speedup vs baseline: 1.0455x; 1.0218x over previous
//
#include <hip/hip_runtime.h>
#include <hip/hip_bf16.h>

#define M_NODES 32768

using f16x8 = __attribute__((ext_vector_type(8))) _Float16;
using f16x4 = __attribute__((ext_vector_type(4))) _Float16;
using f32x4 = __attribute__((ext_vector_type(4))) float;
typedef unsigned short u16;
typedef unsigned int   u32;

__device__ __forceinline__ float h2f(u16 h){
  return (float)__builtin_bit_cast(_Float16, h);
}
// tanh(x) = 1 - 2/(e^{2x}+1); saturates correctly at +-inf
__device__ __forceinline__ float tanh_fast(float x){
  float t = __builtin_amdgcn_exp2f(x * 2.8853900817779268f);
  return 1.0f - 2.0f * __builtin_amdgcn_rcpf(t + 1.0f);
}
__device__ __forceinline__ u16 f2h(float f){
  _Float16 h = (_Float16)f;
  return __builtin_bit_cast(u16, h);
}

// ---------------- prep: fp32 weights -> fp16 transposed Wt[n][k] in d_ws ----------------
struct PrepPtrs { const float* p[16]; };

__global__ void prep_kernel(PrepPtrs pp, u16* ws){
  const int Bc[16] = {1,6,6,6,3,3,3,3,3,3,3,3,3,3,3,3};
  const int Kc[16] = {32,128,128,128,256,256,256,128,128,128,256,256,256,128,128,128};
  const int Nc[16] = {128,128,128,128,256,256,128,128,128,128,256,256,128,128,128,128};
  const int tot = 1576960;
  for (int i = blockIdx.x*blockDim.x + threadIdx.x; i < tot; i += gridDim.x*blockDim.x){
    int e = i, s = 0;
    while (true){ int sz = Bc[s]*Kc[s]*Nc[s]; if (e < sz) break; e -= sz; ++s; }
    int K = Kc[s], N = Nc[s];
    int kn = K*N;
    int b = e / kn; int r2 = e - b*kn;
    int n = r2 / K; int k = r2 - n*K;
    float v = pp.p[s][(size_t)b*kn + (size_t)k*N + n];
    ws[i] = f2h(v);
  }
}

// ---------------- front 0: e0 = tanh(feats0 @ embed_w + b) (fp32 vector ALU, exact) ----------------
__global__ __launch_bounds__(256) void front0_kernel(const float* __restrict__ feats,
                                                     const float* __restrict__ ew,
                                                     const float* __restrict__ eb,
                                                     float* __restrict__ out){
  __shared__ float fl[2048]; // 64 rows x 32 feats
  const int brow = blockIdx.x * 64;
  const float* f0 = feats + (size_t)brow*32;
#pragma unroll
  for (int it = 0; it < 2; ++it){
    int idx = threadIdx.x + it*256;
    *(float4*)(&fl[idx*4]) = *(const float4*)(f0 + idx*4);
  }
  __syncthreads();
  const int col = threadIdx.x & 127, rh = threadIdx.x >> 7;
  float w[32];
#pragma unroll
  for (int k = 0; k < 32; ++k) w[k] = ew[k*128 + col];
  const float bv = eb[col];
  for (int r = 0; r < 32; ++r){
    int row = rh*32 + r;
    float acc = bv;
#pragma unroll
    for (int k = 0; k < 32; ++k) acc += fl[row*32 + k] * w[k];
    out[(size_t)(brow + row)*128 + col] = tanh_fast(acc);
  }
}

// ---------------- weight ring: 2-panel register prefetch, hoisted ACROSS stages ----------------
struct WRing {
  const u16* wrow[4];
  f16x8 b0[4], b1[4];
};

template<int N, int WS, int NP>
__device__ __forceinline__ void wpreload(WRing& R, const u16* __restrict__ wt, int phase){
  const int tid  = threadIdx.x;
  const int lane = tid & 63, nq = tid >> 6;
  const int q = lane >> 4, c = lane & 15;
  constexpr int NT = N / 64;
  const int msk = NP - 1;
  const int p0 = phase & msk, p1 = (phase + 1) & msk;
#pragma unroll
  for (int j = 0; j < NT; ++j){
    int nt = nq*2 + (j & 1) + (j >> 1) * 8;
    R.wrow[j] = wt + (size_t)(nt*16 + c)*WS + q*8;
  }
#pragma unroll
  for (int j = 0; j < NT; ++j) R.b0[j] = *(const f16x8*)(R.wrow[j] + p0*32);
#pragma unroll
  for (int j = 0; j < NT; ++j) R.b1[j] = *(const f16x8*)(R.wrow[j] + p1*32);
}

// ---------------- generic MFMA stage (fp16 MFMA, fp32 accumulate) ----------------
// 64-row block, 4 waves. SWAPPED OPERANDS mfma(W, act). All activations carried
// fp16 (drop-lo: the f32 hi/lo-split carriers removed -- saves 2x MFMA + 384
// split-VALU/thread on 3 stages; error budget ~0.015 < 0.02, see journal).
// AMODE: 0 = act fp16 in LDS, 1 = act fp32 in LDS -> hi/lo split (legacy, unused)
// RESMODE: 0 none, 1 fp16 res col<128 only, 2 fp16 res, 3 fp32 res
// OUTMODE: 0 fp16 LDS, 1 fp32 LDS, 2 fp32 global (final)
template<int KLOOP, int N, int WS, int AMODE, int RESMODE, int OUTMODE, bool INPLACE,
         int NN, int NWS, int NNP>
__device__ __forceinline__ void mm_stage(const u16* inA, u16* outB, const u16* resB,
                                         const float* __restrict__ bias, float* gout,
                                         int phase, WRing& cur, WRing& nxt,
                                         const u16* __restrict__ wtnext)
{
  const int tid  = threadIdx.x;
  const int lane = tid & 63, nq = tid >> 6;
  const int q = lane >> 4, c = lane & 15;
  constexpr int NT = N / 64;      // col tiles per wave (2 or 4)
  constexpr int NP = KLOOP / 32;  // k-panels (4 or 8)
  constexpr bool ABURST = (AMODE == 0 && NP == 4);
  const float* inAf = (const float*)inA;
  float*       outF = (float*)outB;
  const float* resF = (const float*)resB;
  const int msk = NP - 1;
  const int ph = phase & msk;

  f32x4 acc[4][NT];
#pragma unroll
  for (int m = 0; m < 4; ++m)
#pragma unroll
    for (int j = 0; j < NT; ++j) acc[m][j] = (f32x4){0.f,0.f,0.f,0.f};

  // A-burst: all 16 activation fragments in one load wave
  f16x8 aall[ABURST ? 16 : 1];
  if (ABURST){
#pragma unroll
    for (int kp = 0; kp < 4; ++kp){
      int kpp = (ph + kp) & 3;
#pragma unroll
      for (int m = 0; m < 4; ++m)
        aall[kp*4 + m] = *(const f16x8*)(&inA[(m*16 + c)*264 + kpp*32 + q*8]);
    }
  }

#pragma unroll
  for (int kp = 0; kp < NP; ++kp){
    const int kpp = (ph + kp) & msk;
    f16x8 bc[NT];
    if ((kp & 1) == 0){
#pragma unroll
      for (int j = 0; j < NT; ++j) bc[j] = cur.b0[j];
    } else {
#pragma unroll
      for (int j = 0; j < NT; ++j) bc[j] = cur.b1[j];
    }
    if (kp + 2 < NP){
      int kn = (ph + kp + 2) & msk;
      if ((kp & 1) == 0){
#pragma unroll
        for (int j = 0; j < NT; ++j) cur.b0[j] = *(const f16x8*)(cur.wrow[j] + kn*32);
      } else {
#pragma unroll
        for (int j = 0; j < NT; ++j) cur.b1[j] = *(const f16x8*)(cur.wrow[j] + kn*32);
      }
    }
#pragma unroll
    for (int m = 0; m < 4; ++m){
      if (AMODE == 0){
        f16x8 af;
        if (ABURST) af = aall[kp*4 + m];
        else        af = *(const f16x8*)(&inA[(m*16 + c)*264 + kpp*32 + q*8]);
#pragma unroll
        for (int j = 0; j < NT; ++j)
          acc[m][j] = __builtin_amdgcn_mfma_f32_16x16x32_f16(bc[j], af, acc[m][j], 0, 0, 0);
      } else {
        const float* ap = inAf + (m*16 + c)*132 + kpp*32 + q*8;
        float4 x0 = *(const float4*)(ap);
        float4 x1 = *(const float4*)(ap + 4);
        float xs[8] = {x0.x,x0.y,x0.z,x0.w,x1.x,x1.y,x1.z,x1.w};
        f16x8 ah, al;
#pragma unroll
        for (int k = 0; k < 8; ++k){
          _Float16 hi = (_Float16)xs[k];
          ah[k] = hi;
          al[k] = (_Float16)(xs[k] - (float)hi);
        }
#pragma unroll
        for (int j = 0; j < NT; ++j){
          acc[m][j] = __builtin_amdgcn_mfma_f32_16x16x32_f16(bc[j], ah, acc[m][j], 0, 0, 0);
          acc[m][j] = __builtin_amdgcn_mfma_f32_16x16x32_f16(bc[j], al, acc[m][j], 0, 0, 0);
        }
      }
    }
  }
  // hoisted preload of NEXT stage's weight panels (lands during epilogue+barrier)
  if constexpr (NN > 0) wpreload<NN, NWS, NNP>(nxt, wtnext, phase);
  if (INPLACE) __syncthreads();
  // vectorized epilogue: per (j,m) one row (m*16+c), 4 consecutive cols
#pragma unroll
  for (int j = 0; j < NT; ++j){
    int nt = nq*2 + (j & 1) + (j >> 1) * 8;
    int col0 = nt*16 + q*4;
    float4 bq = *(const float4*)(bias + col0);
    float bvv[4] = {bq.x, bq.y, bq.z, bq.w};
#pragma unroll
    for (int m = 0; m < 4; ++m){
      int row = m*16 + c;
      float v[4];
#pragma unroll
      for (int r = 0; r < 4; ++r) v[r] = tanh_fast(acc[m][j][r] + bvv[r]);
      if (RESMODE == 2 || (RESMODE == 1 && j < 2)){
        f16x4 rv = *(const f16x4*)(&resB[row*264 + col0]);
#pragma unroll
        for (int r = 0; r < 4; ++r) v[r] += (float)rv[r];
      } else if (RESMODE == 3){
        float4 rf = *(const float4*)(&resF[row*132 + col0]);
        v[0] += rf.x; v[1] += rf.y; v[2] += rf.z; v[3] += rf.w;
      }
      if (OUTMODE == 2){
        float4 o = {v[0], v[1], v[2], v[3]};
        *(float4*)(&gout[(size_t)row*128 + col0]) = o;
      } else if (OUTMODE == 1){
        float4 o = {v[0], v[1], v[2], v[3]};
        *(float4*)(&outF[row*132 + col0]) = o;
      } else {
        f16x4 h;
#pragma unroll
        for (int r = 0; r < 4; ++r) h[r] = (_Float16)v[r];
        *(f16x4*)(&outB[row*264 + col0]) = h;
      }
    }
  }
  __syncthreads();
}

// embed stage: act from global fp32 feats (K=32) hi/lo split (exact inputs); weights from ring.b0
__device__ __forceinline__ void embed_stage(const float* __restrict__ featsRow,
                                            u16* outB, const float* __restrict__ bias,
                                            int phase, WRing& cur, WRing& nxt,
                                            const u16* __restrict__ wtnext)
{
  const int tid  = threadIdx.x;
  const int lane = tid & 63, nq = tid >> 6;
  const int q = lane >> 4, c = lane & 15;
  f32x4 acc[4][2];
#pragma unroll
  for (int m = 0; m < 4; ++m){ acc[m][0] = (f32x4){0,0,0,0}; acc[m][1] = (f32x4){0,0,0,0}; }
#pragma unroll
  for (int m = 0; m < 4; ++m){
    int row = m*16 + c;
    const float* fp = featsRow + (size_t)row*32 + q*8;
    float4 a0 = *(const float4*)(fp);
    float4 a1 = *(const float4*)(fp + 4);
    float xs[8] = {a0.x,a0.y,a0.z,a0.w,a1.x,a1.y,a1.z,a1.w};
    f16x8 ah, al;
#pragma unroll
    for (int k = 0; k < 8; ++k){
      _Float16 hi = (_Float16)xs[k];
      ah[k] = hi;
      al[k] = (_Float16)(xs[k] - (float)hi);
    }
#pragma unroll
    for (int j = 0; j < 2; ++j){
      acc[m][j] = __builtin_amdgcn_mfma_f32_16x16x32_f16(cur.b0[j], ah, acc[m][j], 0, 0, 0);
      acc[m][j] = __builtin_amdgcn_mfma_f32_16x16x32_f16(cur.b0[j], al, acc[m][j], 0, 0, 0);
    }
  }
  wpreload<256, 256, 4>(nxt, wtnext, phase);   // next = comb_wide w1
#pragma unroll
  for (int j = 0; j < 2; ++j){
    int nt = nq*2 + j;
    int col0 = nt*16 + q*4;
    float4 bq = *(const float4*)(bias + col0);
    float bvv[4] = {bq.x, bq.y, bq.z, bq.w};
#pragma unroll
    for (int m = 0; m < 4; ++m){
      int row = m*16 + c;
      f16x4 h;
#pragma unroll
      for (int r = 0; r < 4; ++r) h[r] = (_Float16)tanh_fast(acc[m][j][r] + bvv[r]);
      *(f16x4*)(&outB[row*264 + col0]) = h;
    }
  }
  __syncthreads();
}

struct FrontArgs {
  const float* feats; const int* pred;
  const u16* ws;
  float* out;
  const float* embed_b;
  const float* mp_b1; const float* mp_b2; const float* mp_b3;
  const float* cw_b1; const float* cw_b2; const float* cw_b3;
  const float* ch_b1; const float* ch_b2; const float* ch_b3;
  const float* nw_b1; const float* nw_b2; const float* nw_b3;
  const float* nh_b1; const float* nh_b2; const float* nh_b3;
  int l, d;
};

// LDS: P[64][264] u16 + Q[64][264] u16 = 67584 B dynamic -> 2 blocks/CU
__global__ __launch_bounds__(256, 2) void front_kernel(FrontArgs A)
{
  extern __shared__ u16 lds[];
  u16* P  = lds;
  u16* Q  = lds + 16896;
  const int brow = blockIdx.x * 64;
  const int d = A.d;
  const u16* ws = A.ws;
  const int ph = blockIdx.x;   // per-block K-panel phase
  const int d0 = d*2, d1 = d*2 + 1;

  WRing rA, rB;
  // stage-1 weights in flight while the gather runs
  wpreload<128, 128, 4>(rA, ws + 4096 + (size_t)d0*16384, ph);

  // ---- gather: s = sum_k prev[idx[m][k]] -> P as f16 [64][264] ----
  {
    const float* prev = A.out + (size_t)(A.l - 1) * M_NODES * 128;
    const int c4 = threadIdx.x & 31;  // float4 column group
    const int r0 = threadIdx.x >> 5;  // 8 rows in flight
#pragma unroll
    for (int rr = 0; rr < 8; ++rr){
      int row = r0 + rr*8;
      const int* ip = A.pred + ((size_t)(A.l - 1) * M_NODES + brow + row) * 8;
      float sx=0.f, sy=0.f, sz=0.f, sw=0.f;
#pragma unroll
      for (int p = 0; p < 8; ++p){
        const float4 v = *(const float4*)(prev + (size_t)ip[p]*128 + c4*4);
        sx += v.x; sy += v.y; sz += v.z; sw += v.w;
      }
      f16x4 o;
      o[0] = (_Float16)sx; o[1] = (_Float16)sy; o[2] = (_Float16)sz; o[3] = (_Float16)sw;
      *(f16x4*)(&P[row*264 + c4*4]) = o;
    }
  }
  __syncthreads();

  // 1. h1 = tanh(s @ w1)               A=P.f16 -> Q.f16
  mm_stage<128,128,128, 0,0,0,false, 128,128,4>(P, Q, nullptr, A.mp_b1 + d0*128, nullptr, ph, rA, rB, ws + 102400 + (size_t)d0*16384);
  // 2. h2s = tanh(h1 @ w2) + s         A=Q.f16, res=P.f16 -> P.f16 (per-thread identity, safe)
  mm_stage<128,128,128, 0,2,0,false, 128,128,4>(Q, P, P, A.mp_b2 + d0*128, nullptr, ph, rB, rA, ws + 200704 + (size_t)d0*16384);
  // 3. r1 = tanh(h2s @ w3)             A=P.f16 -> Q.f16
  mm_stage<128,128,128, 0,0,0,false, 128,128,4>(P, Q, nullptr, A.mp_b3 + d0*128, nullptr, ph, rA, rB, ws + 4096 + (size_t)d1*16384);
  // 4. h1b = tanh(r1 @ w1)             A=Q.f16 -> P.f16
  mm_stage<128,128,128, 0,0,0,false, 128,128,4>(Q, P, nullptr, A.mp_b1 + d1*128, nullptr, ph, rB, rA, ws + 102400 + (size_t)d1*16384);
  // 5. h2r = tanh(h1b @ w2) + r1       A=P.f16, res=Q.f16 -> P.f16 (INPLACE)
  mm_stage<128,128,128, 0,2,0,true , 128,128,4>(P, P, Q, A.mp_b2 + d1*128, nullptr, ph, rA, rB, ws + 200704 + (size_t)d1*16384);
  // 6. r = tanh(h2r @ w3)              A=P.f16 -> Q.f16[128:256); next = embed (K=32, 1 panel)
  mm_stage<128,128,128, 0,0,0,false, 128,32,1>(P, Q + 128, nullptr, A.mp_b3 + d1*128, nullptr, ph, rB, rA, ws);
  // 7. e -> Q.f16[0:128)   (Q = [e | r]); next = cw1
  embed_stage(A.feats + ((size_t)A.l * M_NODES + brow) * 32, Q, A.embed_b, ph, rA, rB, ws + 299008 + (size_t)d*65536);
  // ---- comb_wide resnet on [e,0] (zero-trick: K=128) ----
  mm_stage<128,256,256, 0,0,0,false, 256,256,8>(Q, P, nullptr, A.cw_b1 + d*256, nullptr, ph, rB, rA, ws + 495616 + (size_t)d*65536);
  mm_stage<256,256,256, 0,1,0,true , 128,256,8>(P, P, Q, A.cw_b2 + d*256, nullptr, ph, rA, rB, ws + 692224 + (size_t)d*32768);
  mm_stage<256,128,256, 0,0,0,false, 128,128,4>(P, Q, nullptr, A.cw_b3 + d*128, nullptr, ph, rB, rA, ws + 790528 + (size_t)d*16384);
  // ---- comb_h resnet ----
  mm_stage<128,128,128, 0,0,0,false, 128,128,4>(Q, P, nullptr, A.ch_b1 + d*128, nullptr, ph, rA, rB, ws + 839680 + (size_t)d*16384);
  mm_stage<128,128,128, 0,2,0,true , 128,128,4>(P, P, Q, A.ch_b2 + d*128, nullptr, ph, rB, rA, ws + 888832 + (size_t)d*16384);
  mm_stage<128,128,128, 0,0,0,false, 256,256,8>(P, Q, nullptr, A.ch_b3 + d*128, nullptr, ph, rA, rB, ws + 937984 + (size_t)d*65536);
  // ---- node_wide resnet on x2 = [e''|r] in Q ----
  mm_stage<256,256,256, 0,0,0,false, 256,256,8>(Q, P, nullptr, A.nw_b1 + d*256, nullptr, ph, rB, rA, ws + 1134592 + (size_t)d*65536);
  mm_stage<256,256,256, 0,2,0,true , 128,256,8>(P, P, Q, A.nw_b2 + d*256, nullptr, ph, rA, rB, ws + 1331200 + (size_t)d*32768);
  mm_stage<256,128,256, 0,0,0,false, 128,128,4>(P, Q, nullptr, A.nw_b3 + d*128, nullptr, ph, rB, rA, ws + 1429504 + (size_t)d*16384);
  // ---- node_h resnet; final writes fp32 to global ----
  mm_stage<128,128,128, 0,0,0,false, 128,128,4>(Q, P, nullptr, A.nh_b1 + d*128, nullptr, ph, rA, rB, ws + 1478656 + (size_t)d*16384);
  mm_stage<128,128,128, 0,2,0,true , 128,128,4>(P, P, Q, A.nh_b2 + d*128, nullptr, ph, rB, rA, ws + 1527808 + (size_t)d*16384);
  float* gout = A.out + ((size_t)A.l * M_NODES + brow) * 128;
  mm_stage<128,128,128, 0,0,2,false, 0,0,1>(P, nullptr, nullptr, A.nh_b3 + d*128, gout, ph, rA, rB, nullptr);
}

extern "C" void kernel_launch(void* const* d_in, const int* in_sizes, int n_in,
                              void* d_out, int out_size, void* d_ws, size_t ws_size,
                              hipStream_t stream)
{
  (void)in_sizes; (void)n_in; (void)out_size; (void)ws_size;
  const float* feats = (const float*)d_in[0];
  const int*   pred  = (const int*)d_in[1];
  u16*   ws  = (u16*)d_ws;
  float* out = (float*)d_out;

  PrepPtrs pp;
  const int wIdx[16] = {2,4,6,8,10,12,14,16,18,20,22,24,26,28,30,32};
  for (int i = 0; i < 16; ++i) pp.p[i] = (const float*)d_in[wIdx[i]];
  prep_kernel<<<2048, 256, 0, stream>>>(pp, ws);

  front0_kernel<<<M_NODES/64, 256, 0, stream>>>(feats, (const float*)d_in[2], (const float*)d_in[3], out);

  const size_t LDSB = (size_t)(2*64*264) * sizeof(u16); // 67584 B
  (void)hipFuncSetAttribute((const void*)front_kernel,
                            hipFuncAttributeMaxDynamicSharedMemorySize, (int)LDSB);

  FrontArgs A;
  A.feats = feats; A.pred = pred; A.ws = ws; A.out = out;
  A.embed_b = (const float*)d_in[3];
  A.mp_b1 = (const float*)d_in[5];  A.mp_b2 = (const float*)d_in[7];  A.mp_b3 = (const float*)d_in[9];
  A.cw_b1 = (const float*)d_in[11]; A.cw_b2 = (const float*)d_in[13]; A.cw_b3 = (const float*)d_in[15];
  A.ch_b1 = (const float*)d_in[17]; A.ch_b2 = (const float*)d_in[19]; A.ch_b3 = (const float*)d_in[21];
  A.nw_b1 = (const float*)d_in[23]; A.nw_b2 = (const float*)d_in[25]; A.nw_b3 = (const float*)d_in[27];
  A.nh_b1 = (const float*)d_in[29]; A.nh_b2 = (const float*)d_in[31]; A.nh_b3 = (const float*)d_in[33];

  for (int l = 1; l < 8; ++l){
    A.l = l;
    A.d = (l - 1 < 2) ? (l - 1) : 2;
    front_kernel<<<M_NODES/64, 256, LDSB, stream>>>(A);
  }
}